// Round 1
// baseline (121.373 us; speedup 1.0000x reference)
//
#include <hip/hip_runtime.h>
#include <math.h>

// ComplexEMA: B=2, D=1024, N=16, L=4096.
// y[b,d,l] = Re( sum_n gp[d,n] * h[d,n,l] ) + omega[d]*x[b,d,l]
//   h[n,l] = q[n]*h[n,l-1] + x[l],   q = radius*e^{i phi}, gp = gamma*scale*p
// One 64-lane block per (b,d). Each lane owns a 64-elem chunk:
//   pass A: local scan from zero; Kogge-Stone inter-lane scan with q^64;
//   pass C: re-run with carry, write y.

#define Bq 2
#define Dq 1024
#define Nq 16
#define Lq 4096

__global__ __launch_bounds__(64) void cema_kernel(
    const float* __restrict__ x,
    const float* __restrict__ alpha,
    const float* __restrict__ delta,
    const float* __restrict__ theta,
    const float* __restrict__ gmr,
    const float* __restrict__ gmi,
    const float* __restrict__ omg,
    float* __restrict__ out)
{
    __shared__ float xs[64 * 65];            // 64 chunks x 64 elems, +1 pad
    __shared__ float cqr[Nq], cqi[Nq], cgr[Nq], cgi[Nq], cm64r[Nq], cm64i[Nq];
    __shared__ float comega;

    const int bd   = blockIdx.x;             // 0..2047
    const int d    = bd & (Dq - 1);
    const int lane = threadIdx.x;            // 0..63

    const float* xp = x + (size_t)bd * Lq;
    float*       yp = out + (size_t)bd * Lq;

    // ---- stage x into LDS (padded chunks), coalesced float4 loads ----
    #pragma unroll
    for (int i = 0; i < Lq / (64 * 4); ++i) {            // 16 iters
        int e = i * 256 + lane * 4;
        float4 v = *reinterpret_cast<const float4*>(xp + e);
        int chunk = e >> 6, pos = e & 63;
        float* dst = &xs[chunk * 65 + pos];
        dst[0] = v.x; dst[1] = v.y; dst[2] = v.z; dst[3] = v.w;
    }

    // ---- coefficients (precise math; once per block) ----
    if (lane < Nq) {
        int n = lane;
        float th  = theta[d];
        float f   = 1.f / (1.f + expf(-th));             // sigmoid(theta)
        float phi = (float)(n + 1) * f * (float)(2.0 * M_PI / (double)Nq);
        float a   = 1.f / (1.f + expf(-alpha[d * Nq + n]));
        float dd  = 1.f / (1.f + expf(-delta[d * Nq + n]));
        float p   = a;
        float radius = fminf(1.f - a * dd, 1.f);
        float s, c;
        sincosf(phi, &s, &c);
        float qr = radius * c, qi = radius * s;
        cqr[n] = qr; cqi[n] = qi;
        const float scale = 0.25f;                        // 1/sqrt(16)
        cgr[n] = gmr[d * Nq + n] * scale * p;
        cgi[n] = gmi[d * Nq + n] * scale * p;
        // q^64 via 6 complex squarings
        float mr = qr, mi = qi;
        #pragma unroll
        for (int k = 0; k < 6; ++k) {
            float nr = mr * mr - mi * mi;
            float ni = 2.f * mr * mi;
            mr = nr; mi = ni;
        }
        cm64r[n] = mr; cm64i[n] = mi;
    }
    if (lane == 0) comega = omg[d];
    __syncthreads();

    // ---- registers: per-mode coefficients + states ----
    float qr[Nq], qi[Nq], hr[Nq], hi_[Nq];
    #pragma unroll
    for (int n = 0; n < Nq; ++n) {
        qr[n] = cqr[n]; qi[n] = cqi[n];
        hr[n] = 0.f; hi_[n] = 0.f;
    }

    // ---- pass A: local recurrence over own chunk from zero state ----
    const float* xc = &xs[lane * 65];
    for (int t = 0; t < 64; ++t) {
        float xv = xc[t];
        #pragma unroll
        for (int n = 0; n < Nq; ++n) {
            float nr = fmaf(qr[n], hr[n], fmaf(-qi[n], hi_[n], xv));
            float ni = fmaf(qr[n], hi_[n], qi[n] * hr[n]);
            hr[n] = nr; hi_[n] = ni;
        }
    }

    // ---- Kogge-Stone scan across lanes (multiplier q^64, squared per step) ----
    #pragma unroll
    for (int n = 0; n < Nq; ++n) {
        float mr = cm64r[n], mi = cm64i[n];
        float vr = hr[n], vi = hi_[n];
        #pragma unroll
        for (int s = 1; s < 64; s <<= 1) {
            float ur = __shfl_up(vr, s, 64);
            float ui = __shfl_up(vi, s, 64);
            if (lane >= s) {
                vr = fmaf(mr, ur, fmaf(-mi, ui, vr));
                vi = fmaf(mr, ui, fmaf(mi, ur, vi));
            }
            float t2 = mr * mr - mi * mi;
            mi = 2.f * mr * mi;
            mr = t2;
        }
        hr[n] = vr; hi_[n] = vi;
    }
    // exclusive carry: H[lane-1] (zero for lane 0)
    #pragma unroll
    for (int n = 0; n < Nq; ++n) {
        float cr = __shfl_up(hr[n], 1, 64);
        float ci = __shfl_up(hi_[n], 1, 64);
        hr[n]  = (lane > 0) ? cr : 0.f;
        hi_[n] = (lane > 0) ? ci : 0.f;
    }

    // ---- pass C: re-run with carry, emit y into LDS (overwrite x) ----
    float gpr[Nq], gpi[Nq];
    #pragma unroll
    for (int n = 0; n < Nq; ++n) { gpr[n] = cgr[n]; gpi[n] = cgi[n]; }
    float om = comega;

    float* xcw = &xs[lane * 65];
    for (int t = 0; t < 64; ++t) {
        float xv  = xcw[t];
        float acc = om * xv;
        #pragma unroll
        for (int n = 0; n < Nq; ++n) {
            float nr = fmaf(qr[n], hr[n], fmaf(-qi[n], hi_[n], xv));
            float ni = fmaf(qr[n], hi_[n], qi[n] * hr[n]);
            hr[n] = nr; hi_[n] = ni;
            acc = fmaf(gpr[n], nr, acc);
            acc = fmaf(-gpi[n], ni, acc);
        }
        xcw[t] = acc;
    }
    __syncthreads();

    // ---- coalesced store ----
    #pragma unroll
    for (int i = 0; i < Lq / (64 * 4); ++i) {
        int e = i * 256 + lane * 4;
        int chunk = e >> 6, pos = e & 63;
        const float* src = &xs[chunk * 65 + pos];
        *reinterpret_cast<float4*>(yp + e) = make_float4(src[0], src[1], src[2], src[3]);
    }
}

extern "C" void kernel_launch(void* const* d_in, const int* in_sizes, int n_in,
                              void* d_out, int out_size, void* d_ws, size_t ws_size,
                              hipStream_t stream) {
    const float* x     = (const float*)d_in[0];
    const float* alpha = (const float*)d_in[1];
    const float* delta = (const float*)d_in[2];
    const float* theta = (const float*)d_in[3];
    const float* gmr   = (const float*)d_in[4];
    const float* gmi   = (const float*)d_in[5];
    const float* omg   = (const float*)d_in[6];

    dim3 grid(Bq * Dq);
    dim3 block(64);
    cema_kernel<<<grid, block, 0, stream>>>(x, alpha, delta, theta, gmr, gmi, omg,
                                            (float*)d_out);
}